// Round 1
// baseline (368.907 us; speedup 1.0000x reference)
//
#include <hip/hip_runtime.h>
#include <math.h>

// N=50000, E=400000, U=32, R=32. All fp32 inputs; edge_index int32.
//
// R6 (356.3 us): f16 edge-MLP weights/activations (fp32 accum via v_dot2_f32_f16),
//   LDS 37.9->18.75KB, bump merged into edge kernel.
// R7 (this round; no counters — infra failed; static-theory changes):
//  (A) buf fp32 -> fp16: edge->node stream 307MB -> 154MB round-trip.
//      W3 rows + b3 permuted in prep so outputs emerge in [comp][unit] pair
//      order -> 12 uint4 stores/edge (was 24 float4), node reads coalesced
//      ushorts at +0/+32/+64 halves.
//  (B) node comp_linear LDS reads 13 -> 4 per k: cb packed [k][12]
//      (float4+float4+float2) and Wt interleaved [k][u][4] (1x ds_read_b128).
//      LDS 34 -> 44KB (3 blocks/CU) — loop is instruction-bound, not occ-bound.
//  (C) removed 2 of 3 node barriers (cb traffic is intra-wave; DS in-order).

typedef _Float16 h2 __attribute__((ext_vector_type(2)));
typedef __fp16   p2 __attribute__((ext_vector_type(2)));

__device__ __forceinline__ h2 as_h2(unsigned u){ union{unsigned x; h2 h;} c; c.x=u; return c.h; }
__device__ __forceinline__ unsigned h2bits(h2 h){ union{h2 h; unsigned x;} c; c.h=h; return c.x; }

__device__ __forceinline__ float dot2(h2 a, h2 b, float c){
#if __has_builtin(__builtin_amdgcn_fdot2)
    return __builtin_amdgcn_fdot2(a, b, c, false);
#else
    return c + (float)a.x*(float)b.x + (float)a.y*(float)b.y;
#endif
}

__device__ __forceinline__ h2 pk(float a, float b){
#if __has_builtin(__builtin_amdgcn_cvt_pkrtz)
    union { p2 p; h2 h; } c;
    c.p = __builtin_amdgcn_cvt_pkrtz(a, b);
    return c.h;
#else
    h2 r; r.x=(_Float16)a; r.y=(_Float16)b; return r;
#endif
}

__device__ __forceinline__ float fast_silu(float x){
    return x * __builtin_amdgcn_rcpf(1.0f + __expf(-x));
}

// ---- prep: interleave Wt as [half][k][u][4]={w_l0,w_l1,w_l2,pad}, permute
// ---- b3/W3 rows to [comp][unit] output order, convert W1/W2/W3 to f16 ------
__global__ __launch_bounds__(256) void prep_kernel(
    const float* __restrict__ Wt,
    const float* __restrict__ W1, const float* __restrict__ b1,
    const float* __restrict__ W2, const float* __restrict__ b2,
    const float* __restrict__ W3, const float* __restrict__ b3,
    float* __restrict__ wtI, float* __restrict__ ball, unsigned* __restrict__ whall)
{
    int i = blockIdx.x * 256 + threadIdx.x;
    if (i < 8192) {
        // wtI[h][k][u][c] = Wt[3h+c][u][k]  (c==3 -> pad)
        int h = i >> 12, r = i & 4095, ku = r >> 2, c = r & 3;
        int k = ku >> 5, u = ku & 31;
        wtI[i] = (c < 3) ? Wt[(3*h + c)*1024 + u*32 + k] : 0.0f;
    }
    if (i < 192) {
        float v;
        if (i < 32)      v = b1[i];
        else if (i < 96) v = b2[i-32];
        else {
            int o = i - 96;                       // output slot o' = c*32+u
            v = b3[(o & 31)*3 + (o >> 5)];        // original row m = u*3+c
        }
        ball[i] = v;
    }
    if (i < 9216) {
        float v;
        if (i < 1024)      v = W1[i];
        else if (i < 3072) v = W2[i-1024];
        else {
            int local = i - 3072, rp = local >> 6, k = local & 63;
            v = W3[((rp & 31)*3 + (rp >> 5))*64 + k];   // permuted row
        }
        reinterpret_cast<_Float16*>(whall)[i] = (_Float16)v;
    }
}

// ---- CSR build ---------------------------------------------------------------
__global__ __launch_bounds__(256) void hist_kernel(
    const int* __restrict__ edge_index, int* __restrict__ cnt, int nE)
{
    int e = blockIdx.x * 256 + threadIdx.x;
    if (e < nE) atomicAdd(&cnt[edge_index[nE + e]], 1);
}

__global__ __launch_bounds__(1024) void scanA_kernel(
    const int* __restrict__ cnt, int* __restrict__ rowptr,
    int* __restrict__ csum, int nN)
{
    __shared__ int wsum[16];
    __shared__ int wpre[16];
    int tid = threadIdx.x, lane = tid & 63, wid = tid >> 6;
    int i = blockIdx.x * 1024 + tid;
    int orig = (i < nN) ? cnt[i] : 0;
    int v = orig;
    #pragma unroll
    for (int d = 1; d < 64; d <<= 1) { int o = __shfl_up(v, d); if (lane >= d) v += o; }
    if (lane == 63) wsum[wid] = v;
    __syncthreads();
    if (wid == 0) {
        int s = (lane < 16) ? wsum[lane] : 0;
        #pragma unroll
        for (int d = 1; d < 16; d <<= 1) { int o = __shfl_up(s, d); if (lane >= d) s += o; }
        if (lane < 16) wpre[lane] = s;
    }
    __syncthreads();
    int badd = wid ? wpre[wid - 1] : 0;
    if (i < nN) rowptr[i] = badd + v - orig;
    if (tid == 1023) csum[blockIdx.x] = badd + v;
}

__global__ __launch_bounds__(64) void scanB_kernel(
    int* __restrict__ csum, int* __restrict__ rowptr, int nChunks, int nN)
{
    int lane = threadIdx.x;
    int orig = (lane < nChunks) ? csum[lane] : 0;
    int s = orig;
    #pragma unroll
    for (int d = 1; d < 64; d <<= 1) { int o = __shfl_up(s, d); if (lane >= d) s += o; }
    if (lane < nChunks) csum[lane] = s - orig;
    if (lane == 63) rowptr[nN] = s;
}

__global__ __launch_bounds__(1024) void scanC_kernel(
    const int* __restrict__ csum, int* __restrict__ rowptr, int nN)
{
    int i = blockIdx.x * 1024 + threadIdx.x;
    if (i < nN) rowptr[i] += csum[i >> 10];
}

// ---- edge: f16 MLP (fp32 accum), slot inline, store 96 halves (12 uint4) ----
__global__ __launch_bounds__(256) void edge_mlp_store_kernel(
    const float* __restrict__ edge_attr,
    const float* __restrict__ edge_weight,
    const int* __restrict__ edge_index,
    const int* __restrict__ rowptr,
    int* __restrict__ cursor,
    const unsigned* __restrict__ whall,   // f16 weights: w1[512u] w2[1024u] w3[3072u]
    const float* __restrict__ ball,       // 192 fp32 biases (b3 permuted)
    float* __restrict__ buf, int nE)
{
    __shared__ __align__(16) unsigned swu[4608];
    __shared__ float sb[192];
    int tid = threadIdx.x;
    for (int i = tid; i < 4608; i += 256) swu[i] = whall[i];
    if (tid < 192) sb[tid] = ball[tid];
    __syncthreads();

    int e = blockIdx.x * 256 + tid;
    if (e >= nE) return;

    // load + pack edge_attr row (32 f32 -> 16 h2)
    const float4* rq = reinterpret_cast<const float4*>(edge_attr) + (size_t)e * 8;
    h2 eah[16];
    #pragma unroll
    for (int i = 0; i < 8; ++i) {
        float4 q = rq[i];
        eah[2*i]   = pk(q.x, q.y);
        eah[2*i+1] = pk(q.z, q.w);
    }
    int dst  = edge_index[nE + e];
    int slot = rowptr[dst] + atomicAdd(&cursor[dst], 1);   // start atomic early
    float ew = edge_weight[e];
    float Cc = (ew < 5.0f) ? 0.5f * (__cosf(ew * 0.6283185307179586f) + 1.0f) : 0.0f;

    // layer 1: 32->32, m-pairs (rows are 4 uint4 each)
    h2 h1h[16];
    const uint4* base1 = reinterpret_cast<const uint4*>(swu);
    #pragma unroll
    for (int mp = 0; mp < 16; ++mp) {
        float a0 = sb[2*mp], a1 = sb[2*mp+1];
        const uint4* w0 = base1 + 2*mp*4;
        #pragma unroll
        for (int q = 0; q < 4; ++q) {
            uint4 x = w0[q], y = w0[q+4];
            a0 = dot2(eah[4*q+0], as_h2(x.x), a0);
            a0 = dot2(eah[4*q+1], as_h2(x.y), a0);
            a0 = dot2(eah[4*q+2], as_h2(x.z), a0);
            a0 = dot2(eah[4*q+3], as_h2(x.w), a0);
            a1 = dot2(eah[4*q+0], as_h2(y.x), a1);
            a1 = dot2(eah[4*q+1], as_h2(y.y), a1);
            a1 = dot2(eah[4*q+2], as_h2(y.z), a1);
            a1 = dot2(eah[4*q+3], as_h2(y.w), a1);
        }
        h1h[mp] = pk(fast_silu(a0), fast_silu(a1));
    }

    // layer 2: 32->64
    h2 h2h[32];
    const uint4* base2 = reinterpret_cast<const uint4*>(swu + 512);
    #pragma unroll
    for (int mp = 0; mp < 32; ++mp) {
        float a0 = sb[32 + 2*mp], a1 = sb[32 + 2*mp+1];
        const uint4* w0 = base2 + 2*mp*4;
        #pragma unroll
        for (int q = 0; q < 4; ++q) {
            uint4 x = w0[q], y = w0[q+4];
            a0 = dot2(h1h[4*q+0], as_h2(x.x), a0);
            a0 = dot2(h1h[4*q+1], as_h2(x.y), a0);
            a0 = dot2(h1h[4*q+2], as_h2(x.z), a0);
            a0 = dot2(h1h[4*q+3], as_h2(x.w), a0);
            a1 = dot2(h1h[4*q+0], as_h2(y.x), a1);
            a1 = dot2(h1h[4*q+1], as_h2(y.y), a1);
            a1 = dot2(h1h[4*q+2], as_h2(y.z), a1);
            a1 = dot2(h1h[4*q+3], as_h2(y.w), a1);
        }
        h2h[mp] = pk(fast_silu(a0), fast_silu(a1));
    }

    // layer 3: 64->96 (rows permuted to [comp][unit] order), groups of 4 outputs,
    // pack to h2 and emit one uint4 store per pair of groups (12 stores total).
    unsigned* ob = reinterpret_cast<unsigned*>(buf) + (size_t)slot * 48;
    const uint4* base3 = reinterpret_cast<const uint4*>(swu + 1536);
    unsigned p0 = 0, p1 = 0;
    for (int g = 0; g < 24; ++g) {
        float a0 = sb[96+4*g], a1 = sb[96+4*g+1], a2 = sb[96+4*g+2], a3 = sb[96+4*g+3];
        const uint4* w0 = base3 + 4*g*8;
        #pragma unroll
        for (int q = 0; q < 8; ++q) {
            uint4 x = w0[q], y = w0[q+8], z = w0[q+16], w = w0[q+24];
            a0 = dot2(h2h[4*q+0], as_h2(x.x), a0);
            a0 = dot2(h2h[4*q+1], as_h2(x.y), a0);
            a0 = dot2(h2h[4*q+2], as_h2(x.z), a0);
            a0 = dot2(h2h[4*q+3], as_h2(x.w), a0);
            a1 = dot2(h2h[4*q+0], as_h2(y.x), a1);
            a1 = dot2(h2h[4*q+1], as_h2(y.y), a1);
            a1 = dot2(h2h[4*q+2], as_h2(y.z), a1);
            a1 = dot2(h2h[4*q+3], as_h2(y.w), a1);
            a2 = dot2(h2h[4*q+0], as_h2(z.x), a2);
            a2 = dot2(h2h[4*q+1], as_h2(z.y), a2);
            a2 = dot2(h2h[4*q+2], as_h2(z.z), a2);
            a2 = dot2(h2h[4*q+3], as_h2(z.w), a2);
            a3 = dot2(h2h[4*q+0], as_h2(w.x), a3);
            a3 = dot2(h2h[4*q+1], as_h2(w.y), a3);
            a3 = dot2(h2h[4*q+2], as_h2(w.z), a3);
            a3 = dot2(h2h[4*q+3], as_h2(w.w), a3);
        }
        unsigned q0 = h2bits(pk(fast_silu(a0)*Cc, fast_silu(a1)*Cc));
        unsigned q1 = h2bits(pk(fast_silu(a2)*Cc, fast_silu(a3)*Cc));
        if (g & 1) {
            *reinterpret_cast<uint4*>(ob + 2*(g-1)) = make_uint4(p0, p1, q0, q1);
        } else { p0 = q0; p1 = q1; }
    }
}

// ---- node kernel -------------------------------------------------------------
// wI: [32k][32u][4] = {Wt[l0][u][k], Wt[l1][u][k], Wt[l2][u][k], pad}
// cbn: [32k][12] = {I, A01, A02, A12, S00, S01, S02, S11, S12, S22, pad, pad}
__device__ __forceinline__ void comp_linear(
    const float* __restrict__ wI, const float* __restrict__ cbn,
    int u, float& Il, float* a, float* s)
{
    Il = 0.f; a[0]=a[1]=a[2]=0.f;
    s[0]=s[1]=s[2]=s[3]=s[4]=s[5]=0.f;
    #pragma unroll
    for (int k = 0; k < 32; ++k) {
        float4 w  = *reinterpret_cast<const float4*>(wI + (((k<<5) + u) << 2));
        float4 c0 = *reinterpret_cast<const float4*>(cbn + k*12);
        float4 c1 = *reinterpret_cast<const float4*>(cbn + k*12 + 4);
        float2 c2 = *reinterpret_cast<const float2*>(cbn + k*12 + 8);
        Il   += c0.x * w.x;
        a[0] += c0.y * w.y;
        a[1] += c0.z * w.y;
        a[2] += c0.w * w.y;
        s[0] += c1.x * w.z;
        s[1] += c1.y * w.z;
        s[2] += c1.z * w.z;
        s[3] += c1.w * w.z;
        s[4] += c2.x * w.z;
        s[5] += c2.y * w.z;
    }
}

__device__ __forceinline__ void compose(float Il, const float* a, const float* s, float (&T)[3][3])
{
    T[0][0] =  Il  + s[0]; T[0][1] =  a[0] + s[1]; T[0][2] =  a[1] + s[2];
    T[1][0] = -a[0] + s[1]; T[1][1] =  Il  + s[3]; T[1][2] =  a[2] + s[4];
    T[2][0] = -a[1] + s[2]; T[2][1] = -a[2] + s[4]; T[2][2] =  Il  + s[5];
}

__global__ __launch_bounds__(256) void node_kernel(
    const float* __restrict__ X,
    const float* __restrict__ wtI,
    const int* __restrict__ rowptr,
    const float* __restrict__ buf,
    float* __restrict__ out, int nN)
{
    __shared__ __align__(16) float sWt[8192];
    __shared__ __align__(16) float sC[8][32][12];

    int tid = threadIdx.x;
    for (int i = tid; i < 8192; i += 256) sWt[i] = wtI[i];

    int ln = tid >> 5, u = tid & 31;
    int n  = blockIdx.x * 8 + ln;
    if (n >= nN) n = nN - 1;
    const float* cbn = &sC[ln][0][0];
    float* cw = &sC[ln][u][0];

    int r0 = rowptr[n], r1 = rowptr[n + 1];
    float sIv = 0.f, sAv = 0.f, sSv = 0.f;
    const _Float16* bp = reinterpret_cast<const _Float16*>(buf) + (size_t)r0 * 96 + u;
    for (int i = r0; i < r1; ++i, bp += 96) {
        sIv += (float)bp[0];    // I plane
        sAv += (float)bp[32];   // A plane
        sSv += (float)bp[64];   // S plane
    }

    const float* xp = X + (size_t)n * 288 + u;
    float x[3][3];
    float nrm = 1.0f;
    #pragma unroll
    for (int i = 0; i < 3; ++i)
        #pragma unroll
        for (int j = 0; j < 3; ++j) {
            float v = xp[(i*3 + j) * 32];
            x[i][j] = v; nrm += v * v;
        }
    float inv = 1.0f / nrm;
    #pragma unroll
    for (int i = 0; i < 3; ++i)
        #pragma unroll
        for (int j = 0; j < 3; ++j) x[i][j] *= inv;

    float tI = (x[0][0] + x[1][1] + x[2][2]) * (1.0f/3.0f);
    *reinterpret_cast<float4*>(cw)     = make_float4(tI,
                                                     0.5f * (x[0][1] - x[1][0]),
                                                     0.5f * (x[0][2] - x[2][0]),
                                                     0.5f * (x[1][2] - x[2][1]));
    *reinterpret_cast<float4*>(cw + 4) = make_float4(x[0][0] - tI,
                                                     0.5f * (x[0][1] + x[1][0]),
                                                     0.5f * (x[0][2] + x[2][0]),
                                                     x[1][1] - tI);
    *reinterpret_cast<float2*>(cw + 8) = make_float2(0.5f * (x[1][2] + x[2][1]),
                                                     x[2][2] - tI);
    __syncthreads();   // sWt staging (also publishes cb; only barrier needed)

    float Il, a[3], s[6];
    comp_linear(sWt, cbn, u, Il, a, s);

    float Ym[3][3], Gm[3][3];
    compose(Il, a, s, Ym);
    float am[3] = {a[0]*sAv, a[1]*sAv, a[2]*sAv};
    float sm[6] = {s[0]*sSv, s[1]*sSv, s[2]*sSv, s[3]*sSv, s[4]*sSv, s[5]*sSv};
    compose(Il * sIv, am, sm, Gm);

    float M[3][3]; float np1 = 1.0f;
    #pragma unroll
    for (int i = 0; i < 3; ++i)
        #pragma unroll
        for (int l = 0; l < 3; ++l) {
            float v = 0.f;
            #pragma unroll
            for (int j = 0; j < 3; ++j) v += Ym[i][j]*Gm[j][l] + Gm[i][j]*Ym[j][l];
            M[i][l] = v; np1 += v * v;
        }
    float rinv = 1.0f / np1;
    float tI2 = (M[0][0] + M[1][1] + M[2][2]) * (1.0f/3.0f);

    // cb is private to this 32-lane group; DS ops are wave-ordered, so no
    // block barrier — just stop the compiler from reordering across phases.
    __builtin_amdgcn_wave_barrier();
    *reinterpret_cast<float4*>(cw)     = make_float4(tI2 * rinv,
                                                     0.5f * (M[0][1] - M[1][0]) * rinv,
                                                     0.5f * (M[0][2] - M[2][0]) * rinv,
                                                     0.5f * (M[1][2] - M[2][1]) * rinv);
    *reinterpret_cast<float4*>(cw + 4) = make_float4((M[0][0] - tI2) * rinv,
                                                     0.5f * (M[0][1] + M[1][0]) * rinv,
                                                     0.5f * (M[0][2] + M[2][0]) * rinv,
                                                     (M[1][1] - tI2) * rinv);
    *reinterpret_cast<float2*>(cw + 8) = make_float2(0.5f * (M[1][2] + M[2][1]) * rinv,
                                                     (M[2][2] - tI2) * rinv);
    __builtin_amdgcn_wave_barrier();

    comp_linear(sWt + 4096, cbn, u, Il, a, s);
    float D[3][3];
    compose(Il, a, s, D);

    float* op = out + (size_t)n * 288 + u;
    #pragma unroll
    for (int i = 0; i < 3; ++i)
        #pragma unroll
        for (int l = 0; l < 3; ++l) {
            float v = x[i][l] + D[i][l];
            #pragma unroll
            for (int j = 0; j < 3; ++j) v += D[i][j] * D[j][l];
            op[(i*3 + l) * 32] = v;
        }
}

extern "C" void kernel_launch(void* const* d_in, const int* in_sizes, int n_in,
                              void* d_out, int out_size, void* d_ws, size_t ws_size,
                              hipStream_t stream) {
    const float* X   = (const float*)d_in[0];
    const int*   ei  = (const int*)d_in[1];
    const float* ew  = (const float*)d_in[2];
    const float* ea  = (const float*)d_in[3];
    const float* W1  = (const float*)d_in[4];
    const float* b1  = (const float*)d_in[5];
    const float* W2  = (const float*)d_in[6];
    const float* b2  = (const float*)d_in[7];
    const float* W3  = (const float*)d_in[8];
    const float* b3  = (const float*)d_in[9];
    const float* Wt  = (const float*)d_in[10];

    int nE = in_sizes[2];          // 400000
    int nN = in_sizes[0] / 288;    // 50000
    int nChunks = (nN + 1023) / 1024;

    float* ws       = (float*)d_ws;
    float* wtI      = ws;                        // 8192 floats (interleaved+pad)
    float* ball     = ws + 8192;                 // 192 floats (pad to 256)
    unsigned* whall = (unsigned*)(ws + 8448);    // 4608 uints (9216 f16)
    float* buf      = ws + 8448 + 4608;          // nE*48 floats (= nE*96 halves, 16B-aligned)
    size_t buf_f    = (size_t)nE * 48;
    int* ib     = (int*)(buf + buf_f);
    int* cntA   = ib;                 // nN
    int* cursor = ib + nN;            // nN
    int* rowptr = ib + 2 * nN;        // nN+1
    int* csum   = ib + 3 * nN + 1;    // nChunks (<=64)

    prep_kernel<<<36, 256, 0, stream>>>(Wt, W1, b1, W2, b2, W3, b3, wtI, ball, whall);
    (void)hipMemsetAsync(cntA, 0, (size_t)2 * nN * sizeof(int), stream);
    hist_kernel<<<(nE + 255) / 256, 256, 0, stream>>>(ei, cntA, nE);
    scanA_kernel<<<nChunks, 1024, 0, stream>>>(cntA, rowptr, csum, nN);
    scanB_kernel<<<1, 64, 0, stream>>>(csum, rowptr, nChunks, nN);
    scanC_kernel<<<nChunks, 1024, 0, stream>>>(csum, rowptr, nN);
    edge_mlp_store_kernel<<<(nE + 255) / 256, 256, 0, stream>>>(
        ea, ew, ei, rowptr, cursor, whall, ball, buf, nE);
    node_kernel<<<(nN + 7) / 8, 256, 0, stream>>>(
        X, wtI, rowptr, buf, (float*)d_out, nN);
}

// Round 3
// 323.102 us; speedup vs baseline: 1.1418x; 1.1418x over previous
//
#include <hip/hip_runtime.h>
#include <math.h>

// N=50000, E=400000, U=32, R=32. All fp32 inputs; edge_index int32.
//
// R7 (368.9 us): buf fp16, node comp_linear 4 LDS reads/k, edge f16-dot2 MLP.
//   Counters: edge kernel 123.8us, MfmaUtil 0, VALUBusy 54%, HBM 17%,
//   0 bank conflicts -> LDS-pipe bound on 1152 uniform ds_read_b128
//   weight broadcasts per edge-wave.
// R8 (unmeasured; infra failed): edge MLP -> MFMA (mfma_f32_16x16x32_f16).
//   Transposed formulation: D = W @ actT so weights are the A-operand,
//   held in 72 VGPRs for the whole kernel (zero weight LDS traffic).
//   One wave = 16 edges (B cols). 18 MFMA/tile. Inter-layer D->B transpose
//   via 24 shfl quarter-exchanges. Biases in 768B LDS. buf layout, W3/b3
//   permutation, cursor protocol unchanged -> node kernel untouched.
// R9 (this round): resubmit of R8 (infra failure, no counters). One change:
//   __launch_bounds__(256,2) -> (256): static VGPR demand ~130 > the 128 cap
//   implied by min-2-waves/EU; the cap would force hot-loop scratch spills.
//   ~130-160 VGPRs still gives ~3 waves/SIMD (m98 precedent).

typedef _Float16 h2    __attribute__((ext_vector_type(2)));
typedef __fp16   p2    __attribute__((ext_vector_type(2)));
typedef _Float16 f16x8 __attribute__((ext_vector_type(8)));
typedef float    f32x4 __attribute__((ext_vector_type(4)));

union U8 { unsigned u[4]; uint4 q; f16x8 v; };
union C4 { float4 f; f32x4 v; };

__device__ __forceinline__ h2 as_h2(unsigned u){ union{unsigned x; h2 h;} c; c.x=u; return c.h; }
__device__ __forceinline__ unsigned h2bits(h2 h){ union{h2 h; unsigned x;} c; c.h=h; return c.x; }

__device__ __forceinline__ h2 pk(float a, float b){
#if __has_builtin(__builtin_amdgcn_cvt_pkrtz)
    union { p2 p; h2 h; } c;
    c.p = __builtin_amdgcn_cvt_pkrtz(a, b);
    return c.h;
#else
    h2 r; r.x=(_Float16)a; r.y=(_Float16)b; return r;
#endif
}

__device__ __forceinline__ float fast_silu(float x){
    return x * __builtin_amdgcn_rcpf(1.0f + __expf(-x));
}

// ---- prep ------------------------------------------------------------------
// wtI  : node tensor weights interleaved [half][k][u][4] (node kernel, f32)
// ball : [b1(32) | b2(64) | b3 permuted to o=c*32+u order (96)]  f32
// wfrag: 18 MFMA A-fragments x 64 lanes x 4 u32 (packed f16 pairs)
//   frag 0..1  : W1 (32x32), m = 16f + (l&15), k = 8(l>>4)+2i
//   frag 2..5  : W2 (64x32), m = 16(f-2) + (l&15)
//   frag 6..17 : W3 (96x64) rows permuted (o=c*32+u -> orig row u*3+c),
//                idx=f-6: mt=idx>>1, kh=idx&1, k = 32kh + 8(l>>4)+2i
__global__ __launch_bounds__(256) void prep_kernel(
    const float* __restrict__ Wt,
    const float* __restrict__ W1, const float* __restrict__ b1,
    const float* __restrict__ W2, const float* __restrict__ b2,
    const float* __restrict__ W3, const float* __restrict__ b3,
    float* __restrict__ wtI, float* __restrict__ ball, unsigned* __restrict__ wfrag)
{
    int i = blockIdx.x * 256 + threadIdx.x;
    if (i < 8192) {
        // wtI[h][k][u][c] = Wt[3h+c][u][k]  (c==3 -> pad)
        int h = i >> 12, r = i & 4095, ku = r >> 2, c = r & 3;
        int k = ku >> 5, u = ku & 31;
        wtI[i] = (c < 3) ? Wt[(3*h + c)*1024 + u*32 + k] : 0.0f;
    }
    if (i < 192) {
        float v;
        if (i < 32)      v = b1[i];
        else if (i < 96) v = b2[i-32];
        else {
            int o = i - 96;                       // output slot o = c*32+u
            v = b3[(o & 31)*3 + (o >> 5)];        // original row m = u*3+c
        }
        ball[i] = v;
    }
    if (i < 4608) {
        int f = i >> 8, l = (i >> 2) & 63, wi = i & 3;
        int row = l & 15, qq = l >> 4;
        int kb = 8*qq + 2*wi;
        float v0, v1;
        if (f < 2) {
            int m = 16*f + row;
            v0 = W1[m*32 + kb]; v1 = W1[m*32 + kb + 1];
        } else if (f < 6) {
            int m = 16*(f-2) + row;
            v0 = W2[m*32 + kb]; v1 = W2[m*32 + kb + 1];
        } else {
            int idx = f - 6, mt = idx >> 1, kh = idx & 1;
            int mp = 16*mt + row;
            int om = (mp & 31)*3 + (mp >> 5);
            int k  = 32*kh + kb;
            v0 = W3[om*64 + k]; v1 = W3[om*64 + k + 1];
        }
        wfrag[i] = h2bits(pk(v0, v1));
    }
}

// ---- CSR build ---------------------------------------------------------------
__global__ __launch_bounds__(256) void hist_kernel(
    const int* __restrict__ edge_index, int* __restrict__ cnt, int nE)
{
    int e = blockIdx.x * 256 + threadIdx.x;
    if (e < nE) atomicAdd(&cnt[edge_index[nE + e]], 1);
}

__global__ __launch_bounds__(1024) void scanA_kernel(
    const int* __restrict__ cnt, int* __restrict__ rowptr,
    int* __restrict__ csum, int nN)
{
    __shared__ int wsum[16];
    __shared__ int wpre[16];
    int tid = threadIdx.x, lane = tid & 63, wid = tid >> 6;
    int i = blockIdx.x * 1024 + tid;
    int orig = (i < nN) ? cnt[i] : 0;
    int v = orig;
    #pragma unroll
    for (int d = 1; d < 64; d <<= 1) { int o = __shfl_up(v, d); if (lane >= d) v += o; }
    if (lane == 63) wsum[wid] = v;
    __syncthreads();
    if (wid == 0) {
        int s = (lane < 16) ? wsum[lane] : 0;
        #pragma unroll
        for (int d = 1; d < 16; d <<= 1) { int o = __shfl_up(s, d); if (lane >= d) s += o; }
        if (lane < 16) wpre[lane] = s;
    }
    __syncthreads();
    int badd = wid ? wpre[wid - 1] : 0;
    if (i < nN) rowptr[i] = badd + v - orig;
    if (tid == 1023) csum[blockIdx.x] = badd + v;
}

__global__ __launch_bounds__(64) void scanB_kernel(
    int* __restrict__ csum, int* __restrict__ rowptr, int nChunks, int nN)
{
    int lane = threadIdx.x;
    int orig = (lane < nChunks) ? csum[lane] : 0;
    int s = orig;
    #pragma unroll
    for (int d = 1; d < 64; d <<= 1) { int o = __shfl_up(s, d); if (lane >= d) s += o; }
    if (lane < nChunks) csum[lane] = s - orig;
    if (lane == 63) rowptr[nN] = s;
}

__global__ __launch_bounds__(1024) void scanC_kernel(
    const int* __restrict__ csum, int* __restrict__ rowptr, int nN)
{
    int i = blockIdx.x * 1024 + threadIdx.x;
    if (i < nN) rowptr[i] += csum[i >> 10];
}

// ---- edge: MFMA MLP --------------------------------------------------------
// One wave = 16 edges. Transposed: D[m][e] = sum_k W[m][k] act[e][k] + b[m].
// D layout (m89-verified): col(e)=lane&15, row(m)=(lane>>4)*4+r.
// A/B layout: row/col = lane&15, k = 8*(lane>>4)+j (contiguous k, b128-style).
__global__ __launch_bounds__(256) void edge_mfma_kernel(
    const float* __restrict__ edge_attr,
    const float* __restrict__ edge_weight,
    const int* __restrict__ edge_index,
    const int* __restrict__ rowptr,
    int* __restrict__ cursor,
    const unsigned* __restrict__ wfrag,
    const float* __restrict__ ball,
    float* __restrict__ buf, int nE)
{
    __shared__ __align__(16) float sball[192];
    int tid = threadIdx.x;
    if (tid < 192) sball[tid] = ball[tid];
    __syncthreads();

    int lane = tid & 63;
    int wid  = (blockIdx.x << 2) + (tid >> 6);
    int nW   = gridDim.x << 2;
    int T    = (nE + 15) >> 4;

    // weight fragments -> registers (72 VGPRs), L2-resident reads
    U8 aw[18];
    #pragma unroll
    for (int f = 0; f < 18; ++f)
        aw[f].q = reinterpret_cast<const uint4*>(wfrag)[f*64 + lane];

    int q = lane >> 4, ecol = lane & 15;
    bool hiq = lane >= 32;                      // q>>1
    int sl = ecol + ((lane & 16) << 1);         // e + 32*(q&1)
    int sh = sl + 16;

    unsigned* bufu = reinterpret_cast<unsigned*>(buf);

    // prefetch first tile
    int tile = wid;
    float4 pA = make_float4(0,0,0,0), pB = pA; float pew = 0.f; int pd = 0;
    if (tile < T) {
        int e = tile*16 + ecol; if (e >= nE) e = nE - 1;
        const float* eap = edge_attr + (size_t)e*32 + q*8;
        pA = *reinterpret_cast<const float4*>(eap);
        pB = *reinterpret_cast<const float4*>(eap + 4);
        pew = edge_weight[e];
        if (lane < 16) pd = edge_index[nE + e];
    }

    for (; tile < T; tile += nW) {
        float4 cA = pA, cB = pB; float ew = pew; int d = pd;
        bool ev = (tile*16 + ecol) < nE;

        int nt = tile + nW;
        if (nt < T) {
            int e = nt*16 + ecol; if (e >= nE) e = nE - 1;
            const float* eap = edge_attr + (size_t)e*32 + q*8;
            pA = *reinterpret_cast<const float4*>(eap);
            pB = *reinterpret_cast<const float4*>(eap + 4);
            pew = edge_weight[e];
            if (lane < 16) pd = edge_index[nE + e];
        }
        int rp = 0;
        if (lane < 16) rp = rowptr[d];          // issue early; used after L2

        // B_ea: col=edge, k=8q+j
        U8 bea;
        bea.u[0] = h2bits(pk(cA.x, cA.y));
        bea.u[1] = h2bits(pk(cA.z, cA.w));
        bea.u[2] = h2bits(pk(cB.x, cB.y));
        bea.u[3] = h2bits(pk(cB.z, cB.w));

        // ---- layer 1: h1T(32xE) = silu(W1 @ eaT + b1) ----
        unsigned w1w[4];
        #pragma unroll
        for (int t = 0; t < 2; ++t) {
            C4 c; c.f = *reinterpret_cast<const float4*>(&sball[16*t + 4*q]);
            f32x4 acc = c.v;
            acc = __builtin_amdgcn_mfma_f32_16x16x32_f16(aw[t].v, bea.v, acc, 0, 0, 0);
            w1w[2*t]   = h2bits(pk(fast_silu(acc[0]), fast_silu(acc[1])));
            w1w[2*t+1] = h2bits(pk(fast_silu(acc[2]), fast_silu(acc[3])));
        }

        // transpose D->B: lane (q',e') needs pair p=4q'+w from source lane
        // e' + 16*(2(q'&1)+(w>>1)), register w1w[2*(p>>3)+(w&1)]
        U8 bh1;
        {
            unsigned t0 = (unsigned)__shfl((int)w1w[0], sl), t2 = (unsigned)__shfl((int)w1w[2], sl);
            bh1.u[0] = hiq ? t2 : t0;
            unsigned t1 = (unsigned)__shfl((int)w1w[1], sl), t3 = (unsigned)__shfl((int)w1w[3], sl);
            bh1.u[1] = hiq ? t3 : t1;
            t0 = (unsigned)__shfl((int)w1w[0], sh); t2 = (unsigned)__shfl((int)w1w[2], sh);
            bh1.u[2] = hiq ? t2 : t0;
            t1 = (unsigned)__shfl((int)w1w[1], sh); t3 = (unsigned)__shfl((int)w1w[3], sh);
            bh1.u[3] = hiq ? t3 : t1;
        }

        // ---- layer 2: h2T(64xE) = silu(W2 @ h1T + b2) ----
        unsigned w2w[8];
        #pragma unroll
        for (int t = 0; t < 4; ++t) {
            C4 c; c.f = *reinterpret_cast<const float4*>(&sball[32 + 16*t + 4*q]);
            f32x4 acc = c.v;
            acc = __builtin_amdgcn_mfma_f32_16x16x32_f16(aw[2+t].v, bh1.v, acc, 0, 0, 0);
            w2w[2*t]   = h2bits(pk(fast_silu(acc[0]), fast_silu(acc[1])));
            w2w[2*t+1] = h2bits(pk(fast_silu(acc[2]), fast_silu(acc[3])));
        }

        // transpose -> two B-frags (k-halves of 64): pair p=16h+4q'+w from
        // source lane sl/sh, register w2w[4h+2*(q'>>1)+(w&1)]
        U8 b3f[2];
        #pragma unroll
        for (int h = 0; h < 2; ++h) {
            unsigned ta = (unsigned)__shfl((int)w2w[4*h],   sl), tb = (unsigned)__shfl((int)w2w[4*h+2], sl);
            b3f[h].u[0] = hiq ? tb : ta;
            unsigned tc = (unsigned)__shfl((int)w2w[4*h+1], sl), td = (unsigned)__shfl((int)w2w[4*h+3], sl);
            b3f[h].u[1] = hiq ? td : tc;
            ta = (unsigned)__shfl((int)w2w[4*h],   sh); tb = (unsigned)__shfl((int)w2w[4*h+2], sh);
            b3f[h].u[2] = hiq ? tb : ta;
            tc = (unsigned)__shfl((int)w2w[4*h+1], sh); td = (unsigned)__shfl((int)w2w[4*h+3], sh);
            b3f[h].u[3] = hiq ? td : tc;
        }

        // slot for own column-edge; broadcast to all quarters
        int slot = 0;
        if (lane < 16 && ev) slot = rp + atomicAdd(&cursor[d], 1);
        int slotAll = __shfl(slot, ecol);

        float Cc = (ew < 5.0f) ? 0.5f * (__cosf(ew * 0.6283185307179586f) + 1.0f) : 0.0f;

        // ---- layer 3: out(96xE) = silu(W3p @ h2T + b3p) * Cc ----
        size_t sb = (size_t)slotAll * 48 + 2*q;
        #pragma unroll
        for (int mt = 0; mt < 6; ++mt) {
            C4 c; c.f = *reinterpret_cast<const float4*>(&sball[96 + 16*mt + 4*q]);
            f32x4 acc = c.v;
            acc = __builtin_amdgcn_mfma_f32_16x16x32_f16(aw[6+2*mt].v, b3f[0].v, acc, 0, 0, 0);
            acc = __builtin_amdgcn_mfma_f32_16x16x32_f16(aw[7+2*mt].v, b3f[1].v, acc, 0, 0, 0);
            unsigned p0 = h2bits(pk(fast_silu(acc[0])*Cc, fast_silu(acc[1])*Cc));
            unsigned p1 = h2bits(pk(fast_silu(acc[2])*Cc, fast_silu(acc[3])*Cc));
            if (ev) *reinterpret_cast<uint2*>(bufu + sb + 8*mt) = make_uint2(p0, p1);
        }
    }
}

// ---- node kernel (unchanged from R7) ----------------------------------------
__device__ __forceinline__ void comp_linear(
    const float* __restrict__ wI, const float* __restrict__ cbn,
    int u, float& Il, float* a, float* s)
{
    Il = 0.f; a[0]=a[1]=a[2]=0.f;
    s[0]=s[1]=s[2]=s[3]=s[4]=s[5]=0.f;
    #pragma unroll
    for (int k = 0; k < 32; ++k) {
        float4 w  = *reinterpret_cast<const float4*>(wI + (((k<<5) + u) << 2));
        float4 c0 = *reinterpret_cast<const float4*>(cbn + k*12);
        float4 c1 = *reinterpret_cast<const float4*>(cbn + k*12 + 4);
        float2 c2 = *reinterpret_cast<const float2*>(cbn + k*12 + 8);
        Il   += c0.x * w.x;
        a[0] += c0.y * w.y;
        a[1] += c0.z * w.y;
        a[2] += c0.w * w.y;
        s[0] += c1.x * w.z;
        s[1] += c1.y * w.z;
        s[2] += c1.z * w.z;
        s[3] += c1.w * w.z;
        s[4] += c2.x * w.z;
        s[5] += c2.y * w.z;
    }
}

__device__ __forceinline__ void compose(float Il, const float* a, const float* s, float (&T)[3][3])
{
    T[0][0] =  Il  + s[0]; T[0][1] =  a[0] + s[1]; T[0][2] =  a[1] + s[2];
    T[1][0] = -a[0] + s[1]; T[1][1] =  Il  + s[3]; T[1][2] =  a[2] + s[4];
    T[2][0] = -a[1] + s[2]; T[2][1] = -a[2] + s[4]; T[2][2] =  Il  + s[5];
}

__global__ __launch_bounds__(256) void node_kernel(
    const float* __restrict__ X,
    const float* __restrict__ wtI,
    const int* __restrict__ rowptr,
    const float* __restrict__ buf,
    float* __restrict__ out, int nN)
{
    __shared__ __align__(16) float sWt[8192];
    __shared__ __align__(16) float sC[8][32][12];

    int tid = threadIdx.x;
    for (int i = tid; i < 8192; i += 256) sWt[i] = wtI[i];

    int ln = tid >> 5, u = tid & 31;
    int n  = blockIdx.x * 8 + ln;
    if (n >= nN) n = nN - 1;
    const float* cbn = &sC[ln][0][0];
    float* cw = &sC[ln][u][0];

    int r0 = rowptr[n], r1 = rowptr[n + 1];
    float sIv = 0.f, sAv = 0.f, sSv = 0.f;
    const _Float16* bp = reinterpret_cast<const _Float16*>(buf) + (size_t)r0 * 96 + u;
    for (int i = r0; i < r1; ++i, bp += 96) {
        sIv += (float)bp[0];    // I plane
        sAv += (float)bp[32];   // A plane
        sSv += (float)bp[64];   // S plane
    }

    const float* xp = X + (size_t)n * 288 + u;
    float x[3][3];
    float nrm = 1.0f;
    #pragma unroll
    for (int i = 0; i < 3; ++i)
        #pragma unroll
        for (int j = 0; j < 3; ++j) {
            float v = xp[(i*3 + j) * 32];
            x[i][j] = v; nrm += v * v;
        }
    float inv = 1.0f / nrm;
    #pragma unroll
    for (int i = 0; i < 3; ++i)
        #pragma unroll
        for (int j = 0; j < 3; ++j) x[i][j] *= inv;

    float tI = (x[0][0] + x[1][1] + x[2][2]) * (1.0f/3.0f);
    *reinterpret_cast<float4*>(cw)     = make_float4(tI,
                                                     0.5f * (x[0][1] - x[1][0]),
                                                     0.5f * (x[0][2] - x[2][0]),
                                                     0.5f * (x[1][2] - x[2][1]));
    *reinterpret_cast<float4*>(cw + 4) = make_float4(x[0][0] - tI,
                                                     0.5f * (x[0][1] + x[1][0]),
                                                     0.5f * (x[0][2] + x[2][0]),
                                                     x[1][1] - tI);
    *reinterpret_cast<float2*>(cw + 8) = make_float2(0.5f * (x[1][2] + x[2][1]),
                                                     x[2][2] - tI);
    __syncthreads();   // sWt staging (also publishes cb)

    float Il, a[3], s[6];
    comp_linear(sWt, cbn, u, Il, a, s);

    float Ym[3][3], Gm[3][3];
    compose(Il, a, s, Ym);
    float am[3] = {a[0]*sAv, a[1]*sAv, a[2]*sAv};
    float sm[6] = {s[0]*sSv, s[1]*sSv, s[2]*sSv, s[3]*sSv, s[4]*sSv, s[5]*sSv};
    compose(Il * sIv, am, sm, Gm);

    float M[3][3]; float np1 = 1.0f;
    #pragma unroll
    for (int i = 0; i < 3; ++i)
        #pragma unroll
        for (int l = 0; l < 3; ++l) {
            float v = 0.f;
            #pragma unroll
            for (int j = 0; j < 3; ++j) v += Ym[i][j]*Gm[j][l] + Gm[i][j]*Ym[j][l];
            M[i][l] = v; np1 += v * v;
        }
    float rinv = 1.0f / np1;
    float tI2 = (M[0][0] + M[1][1] + M[2][2]) * (1.0f/3.0f);

    __builtin_amdgcn_wave_barrier();
    *reinterpret_cast<float4*>(cw)     = make_float4(tI2 * rinv,
                                                     0.5f * (M[0][1] - M[1][0]) * rinv,
                                                     0.5f * (M[0][2] - M[2][0]) * rinv,
                                                     0.5f * (M[1][2] - M[2][1]) * rinv);
    *reinterpret_cast<float4*>(cw + 4) = make_float4((M[0][0] - tI2) * rinv,
                                                     0.5f * (M[0][1] + M[1][0]) * rinv,
                                                     0.5f * (M[0][2] + M[2][0]) * rinv,
                                                     (M[1][1] - tI2) * rinv);
    *reinterpret_cast<float2*>(cw + 8) = make_float2(0.5f * (M[1][2] + M[2][1]) * rinv,
                                                     (M[2][2] - tI2) * rinv);
    __builtin_amdgcn_wave_barrier();

    comp_linear(sWt + 4096, cbn, u, Il, a, s);
    float D[3][3];
    compose(Il, a, s, D);

    float* op = out + (size_t)n * 288 + u;
    #pragma unroll
    for (int i = 0; i < 3; ++i)
        #pragma unroll
        for (int l = 0; l < 3; ++l) {
            float v = x[i][l] + D[i][l];
            #pragma unroll
            for (int j = 0; j < 3; ++j) v += D[i][j] * D[j][l];
            op[(i*3 + l) * 32] = v;
        }
}

extern "C" void kernel_launch(void* const* d_in, const int* in_sizes, int n_in,
                              void* d_out, int out_size, void* d_ws, size_t ws_size,
                              hipStream_t stream) {
    const float* X   = (const float*)d_in[0];
    const int*   ei  = (const int*)d_in[1];
    const float* ew  = (const float*)d_in[2];
    const float* ea  = (const float*)d_in[3];
    const float* W1  = (const float*)d_in[4];
    const float* b1  = (const float*)d_in[5];
    const float* W2  = (const float*)d_in[6];
    const float* b2  = (const float*)d_in[7];
    const float* W3  = (const float*)d_in[8];
    const float* b3  = (const float*)d_in[9];
    const float* Wt  = (const float*)d_in[10];

    int nE = in_sizes[2];          // 400000
    int nN = in_sizes[0] / 288;    // 50000
    int nChunks = (nN + 1023) / 1024;

    float* ws       = (float*)d_ws;
    float* wtI      = ws;                        // 8192 floats
    float* ball     = ws + 8192;                 // 192 floats (pad to 256)
    unsigned* wfrag = (unsigned*)(ws + 8448);    // 4608 u32 MFMA weight frags
    float* buf      = ws + 8448 + 4608;          // nE*48 floats (= nE*96 halves)
    size_t buf_f    = (size_t)nE * 48;
    int* ib     = (int*)(buf + buf_f);
    int* cntA   = ib;                 // nN
    int* cursor = ib + nN;            // nN
    int* rowptr = ib + 2 * nN;        // nN+1
    int* csum   = ib + 3 * nN + 1;    // nChunks (<=64)

    prep_kernel<<<36, 256, 0, stream>>>(Wt, W1, b1, W2, b2, W3, b3, wtI, ball, wfrag);
    (void)hipMemsetAsync(cntA, 0, (size_t)2 * nN * sizeof(int), stream);
    hist_kernel<<<(nE + 255) / 256, 256, 0, stream>>>(ei, cntA, nE);
    scanA_kernel<<<nChunks, 1024, 0, stream>>>(cntA, rowptr, csum, nN);
    scanB_kernel<<<1, 64, 0, stream>>>(csum, rowptr, nChunks, nN);
    scanC_kernel<<<nChunks, 1024, 0, stream>>>(csum, rowptr, nN);
    edge_mfma_kernel<<<768, 256, 0, stream>>>(
        ea, ew, ei, rowptr, cursor, wfrag, ball, buf, nE);
    node_kernel<<<(nN + 7) / 8, 256, 0, stream>>>(
        X, wtI, rowptr, buf, (float*)d_out, nN);
}

// Round 4
// 271.018 us; speedup vs baseline: 1.3612x; 1.1922x over previous
//
#include <hip/hip_runtime.h>
#include <math.h>

// N=50000, E=400000, U=32, R=32. All fp32 inputs; edge_index int32.
//
// R9 (323.1 us): edge MLP on MFMA (below top-5 now); node_kernel new #1 at
//   118us: MfmaUtil 0, VALUBusy 43%, HBM 13%, LDS 45KB, occ 30%.
//   Diagnosis: comp_linear issues 256 DS reads/thread (4/k-iter x 32 x 2),
//   ~3072 LDS-pipe cyc/wave x 97.7 waves/CU ~= 125us -> LDS-pipe bound.
// R10 (this round): node comp_linear -> f16 dot2, LDS instrs 256 -> 112:
//   - weights [call][kpair][u][4] h2 -> 1 b128 per 2 k (16KB LDS),
//   - cb f16 tight-packed [k][10] h2 (40B/k) -> 5 b128 per 2 k,
//   - v_dot2_f32_f16 accumulation (f32 acc), RTN f16 casts for cb/weights.
//   Node LDS 45 -> 21.5KB (occupancy ~2x). Predicted node ~80us (VALU-bound).
//   Edge/CSR/buf protocol unchanged.

typedef _Float16 h2    __attribute__((ext_vector_type(2)));
typedef __fp16   p2    __attribute__((ext_vector_type(2)));
typedef _Float16 f16x8 __attribute__((ext_vector_type(8)));
typedef float    f32x4 __attribute__((ext_vector_type(4)));

union U8 { unsigned u[4]; uint4 q; f16x8 v; };
union C4 { float4 f; f32x4 v; };

__device__ __forceinline__ h2 as_h2(unsigned u){ union{unsigned x; h2 h;} c; c.x=u; return c.h; }
__device__ __forceinline__ unsigned h2bits(h2 h){ union{h2 h; unsigned x;} c; c.h=h; return c.x; }

__device__ __forceinline__ float dot2(h2 a, h2 b, float c){
#if __has_builtin(__builtin_amdgcn_fdot2)
    return __builtin_amdgcn_fdot2(a, b, c, false);
#else
    return c + (float)a.x*(float)b.x + (float)a.y*(float)b.y;
#endif
}

__device__ __forceinline__ h2 pk(float a, float b){
#if __has_builtin(__builtin_amdgcn_cvt_pkrtz)
    union { p2 p; h2 h; } c;
    c.p = __builtin_amdgcn_cvt_pkrtz(a, b);
    return c.h;
#else
    h2 r; r.x=(_Float16)a; r.y=(_Float16)b; return r;
#endif
}

// round-to-nearest f16 pack (for node path precision)
__device__ __forceinline__ unsigned pk_rtn(float a, float b){
    union { h2 h; unsigned x; } c;
    c.h.x = (_Float16)a; c.h.y = (_Float16)b;
    return c.x;
}

__device__ __forceinline__ float fast_silu(float x){
    return x * __builtin_amdgcn_rcpf(1.0f + __expf(-x));
}

// ---- prep ------------------------------------------------------------------
// whn  : node tensor weights f16: uint4[2 call][16 kp][32 u], word c<3 =
//        h2{Wt[3*call+c][u][2kp], Wt[3*call+c][u][2kp+1]}, word3 = 0
// ball : [b1(32) | b2(64) | b3 permuted to o=c*32+u order (96)]  f32
// wfrag: 18 MFMA A-fragments x 64 lanes x 4 u32 (packed f16 pairs)
__global__ __launch_bounds__(256) void prep_kernel(
    const float* __restrict__ Wt,
    const float* __restrict__ W1, const float* __restrict__ b1,
    const float* __restrict__ W2, const float* __restrict__ b2,
    const float* __restrict__ W3, const float* __restrict__ b3,
    unsigned* __restrict__ whn, float* __restrict__ ball, unsigned* __restrict__ wfrag)
{
    int i = blockIdx.x * 256 + threadIdx.x;
    if (i < 4096) {
        int call = i >> 11, r = i & 2047, kp = r >> 7, rem = r & 127;
        int u = rem >> 2, c = rem & 3;
        unsigned val = 0;
        if (c < 3) {
            const float* W = Wt + (size_t)(3*call + c)*1024 + u*32 + 2*kp;
            val = pk_rtn(W[0], W[1]);
        }
        whn[i] = val;
    }
    if (i < 192) {
        float v;
        if (i < 32)      v = b1[i];
        else if (i < 96) v = b2[i-32];
        else {
            int o = i - 96;                       // output slot o = c*32+u
            v = b3[(o & 31)*3 + (o >> 5)];        // original row m = u*3+c
        }
        ball[i] = v;
    }
    if (i < 4608) {
        int f = i >> 8, l = (i >> 2) & 63, wi = i & 3;
        int row = l & 15, qq = l >> 4;
        int kb = 8*qq + 2*wi;
        float v0, v1;
        if (f < 2) {
            int m = 16*f + row;
            v0 = W1[m*32 + kb]; v1 = W1[m*32 + kb + 1];
        } else if (f < 6) {
            int m = 16*(f-2) + row;
            v0 = W2[m*32 + kb]; v1 = W2[m*32 + kb + 1];
        } else {
            int idx = f - 6, mt = idx >> 1, kh = idx & 1;
            int mp = 16*mt + row;
            int om = (mp & 31)*3 + (mp >> 5);
            int k  = 32*kh + kb;
            v0 = W3[om*64 + k]; v1 = W3[om*64 + k + 1];
        }
        wfrag[i] = pk_rtn(v0, v1);
    }
}

// ---- CSR build ---------------------------------------------------------------
__global__ __launch_bounds__(256) void hist_kernel(
    const int* __restrict__ edge_index, int* __restrict__ cnt, int nE)
{
    int e = blockIdx.x * 256 + threadIdx.x;
    if (e < nE) atomicAdd(&cnt[edge_index[nE + e]], 1);
}

__global__ __launch_bounds__(1024) void scanA_kernel(
    const int* __restrict__ cnt, int* __restrict__ rowptr,
    int* __restrict__ csum, int nN)
{
    __shared__ int wsum[16];
    __shared__ int wpre[16];
    int tid = threadIdx.x, lane = tid & 63, wid = tid >> 6;
    int i = blockIdx.x * 1024 + tid;
    int orig = (i < nN) ? cnt[i] : 0;
    int v = orig;
    #pragma unroll
    for (int d = 1; d < 64; d <<= 1) { int o = __shfl_up(v, d); if (lane >= d) v += o; }
    if (lane == 63) wsum[wid] = v;
    __syncthreads();
    if (wid == 0) {
        int s = (lane < 16) ? wsum[lane] : 0;
        #pragma unroll
        for (int d = 1; d < 16; d <<= 1) { int o = __shfl_up(s, d); if (lane >= d) s += o; }
        if (lane < 16) wpre[lane] = s;
    }
    __syncthreads();
    int badd = wid ? wpre[wid - 1] : 0;
    if (i < nN) rowptr[i] = badd + v - orig;
    if (tid == 1023) csum[blockIdx.x] = badd + v;
}

__global__ __launch_bounds__(64) void scanB_kernel(
    int* __restrict__ csum, int* __restrict__ rowptr, int nChunks, int nN)
{
    int lane = threadIdx.x;
    int orig = (lane < nChunks) ? csum[lane] : 0;
    int s = orig;
    #pragma unroll
    for (int d = 1; d < 64; d <<= 1) { int o = __shfl_up(s, d); if (lane >= d) s += o; }
    if (lane < nChunks) csum[lane] = s - orig;
    if (lane == 63) rowptr[nN] = s;
}

__global__ __launch_bounds__(1024) void scanC_kernel(
    const int* __restrict__ csum, int* __restrict__ rowptr, int nN)
{
    int i = blockIdx.x * 1024 + threadIdx.x;
    if (i < nN) rowptr[i] += csum[i >> 10];
}

// ---- edge: MFMA MLP (unchanged from R9) -------------------------------------
__global__ __launch_bounds__(256) void edge_mfma_kernel(
    const float* __restrict__ edge_attr,
    const float* __restrict__ edge_weight,
    const int* __restrict__ edge_index,
    const int* __restrict__ rowptr,
    int* __restrict__ cursor,
    const unsigned* __restrict__ wfrag,
    const float* __restrict__ ball,
    float* __restrict__ buf, int nE)
{
    __shared__ __align__(16) float sball[192];
    int tid = threadIdx.x;
    if (tid < 192) sball[tid] = ball[tid];
    __syncthreads();

    int lane = tid & 63;
    int wid  = (blockIdx.x << 2) + (tid >> 6);
    int nW   = gridDim.x << 2;
    int T    = (nE + 15) >> 4;

    U8 aw[18];
    #pragma unroll
    for (int f = 0; f < 18; ++f)
        aw[f].q = reinterpret_cast<const uint4*>(wfrag)[f*64 + lane];

    int q = lane >> 4, ecol = lane & 15;
    bool hiq = lane >= 32;
    int sl = ecol + ((lane & 16) << 1);
    int sh = sl + 16;

    unsigned* bufu = reinterpret_cast<unsigned*>(buf);

    int tile = wid;
    float4 pA = make_float4(0,0,0,0), pB = pA; float pew = 0.f; int pd = 0;
    if (tile < T) {
        int e = tile*16 + ecol; if (e >= nE) e = nE - 1;
        const float* eap = edge_attr + (size_t)e*32 + q*8;
        pA = *reinterpret_cast<const float4*>(eap);
        pB = *reinterpret_cast<const float4*>(eap + 4);
        pew = edge_weight[e];
        if (lane < 16) pd = edge_index[nE + e];
    }

    for (; tile < T; tile += nW) {
        float4 cA = pA, cB = pB; float ew = pew; int d = pd;
        bool ev = (tile*16 + ecol) < nE;

        int nt = tile + nW;
        if (nt < T) {
            int e = nt*16 + ecol; if (e >= nE) e = nE - 1;
            const float* eap = edge_attr + (size_t)e*32 + q*8;
            pA = *reinterpret_cast<const float4*>(eap);
            pB = *reinterpret_cast<const float4*>(eap + 4);
            pew = edge_weight[e];
            if (lane < 16) pd = edge_index[nE + e];
        }
        int rp = 0;
        if (lane < 16) rp = rowptr[d];

        U8 bea;
        bea.u[0] = h2bits(pk(cA.x, cA.y));
        bea.u[1] = h2bits(pk(cA.z, cA.w));
        bea.u[2] = h2bits(pk(cB.x, cB.y));
        bea.u[3] = h2bits(pk(cB.z, cB.w));

        unsigned w1w[4];
        #pragma unroll
        for (int t = 0; t < 2; ++t) {
            C4 c; c.f = *reinterpret_cast<const float4*>(&sball[16*t + 4*q]);
            f32x4 acc = c.v;
            acc = __builtin_amdgcn_mfma_f32_16x16x32_f16(aw[t].v, bea.v, acc, 0, 0, 0);
            w1w[2*t]   = h2bits(pk(fast_silu(acc[0]), fast_silu(acc[1])));
            w1w[2*t+1] = h2bits(pk(fast_silu(acc[2]), fast_silu(acc[3])));
        }

        U8 bh1;
        {
            unsigned t0 = (unsigned)__shfl((int)w1w[0], sl), t2 = (unsigned)__shfl((int)w1w[2], sl);
            bh1.u[0] = hiq ? t2 : t0;
            unsigned t1 = (unsigned)__shfl((int)w1w[1], sl), t3 = (unsigned)__shfl((int)w1w[3], sl);
            bh1.u[1] = hiq ? t3 : t1;
            t0 = (unsigned)__shfl((int)w1w[0], sh); t2 = (unsigned)__shfl((int)w1w[2], sh);
            bh1.u[2] = hiq ? t2 : t0;
            t1 = (unsigned)__shfl((int)w1w[1], sh); t3 = (unsigned)__shfl((int)w1w[3], sh);
            bh1.u[3] = hiq ? t3 : t1;
        }

        unsigned w2w[8];
        #pragma unroll
        for (int t = 0; t < 4; ++t) {
            C4 c; c.f = *reinterpret_cast<const float4*>(&sball[32 + 16*t + 4*q]);
            f32x4 acc = c.v;
            acc = __builtin_amdgcn_mfma_f32_16x16x32_f16(aw[2+t].v, bh1.v, acc, 0, 0, 0);
            w2w[2*t]   = h2bits(pk(fast_silu(acc[0]), fast_silu(acc[1])));
            w2w[2*t+1] = h2bits(pk(fast_silu(acc[2]), fast_silu(acc[3])));
        }

        U8 b3f[2];
        #pragma unroll
        for (int h = 0; h < 2; ++h) {
            unsigned ta = (unsigned)__shfl((int)w2w[4*h],   sl), tb = (unsigned)__shfl((int)w2w[4*h+2], sl);
            b3f[h].u[0] = hiq ? tb : ta;
            unsigned tc = (unsigned)__shfl((int)w2w[4*h+1], sl), td = (unsigned)__shfl((int)w2w[4*h+3], sl);
            b3f[h].u[1] = hiq ? td : tc;
            ta = (unsigned)__shfl((int)w2w[4*h],   sh); tb = (unsigned)__shfl((int)w2w[4*h+2], sh);
            b3f[h].u[2] = hiq ? tb : ta;
            tc = (unsigned)__shfl((int)w2w[4*h+1], sh); td = (unsigned)__shfl((int)w2w[4*h+3], sh);
            b3f[h].u[3] = hiq ? td : tc;
        }

        int slot = 0;
        if (lane < 16 && ev) slot = rp + atomicAdd(&cursor[d], 1);
        int slotAll = __shfl(slot, ecol);

        float Cc = (ew < 5.0f) ? 0.5f * (__cosf(ew * 0.6283185307179586f) + 1.0f) : 0.0f;

        size_t sb = (size_t)slotAll * 48 + 2*q;
        #pragma unroll
        for (int mt = 0; mt < 6; ++mt) {
            C4 c; c.f = *reinterpret_cast<const float4*>(&sball[96 + 16*mt + 4*q]);
            f32x4 acc = c.v;
            acc = __builtin_amdgcn_mfma_f32_16x16x32_f16(aw[6+2*mt].v, b3f[0].v, acc, 0, 0, 0);
            acc = __builtin_amdgcn_mfma_f32_16x16x32_f16(aw[7+2*mt].v, b3f[1].v, acc, 0, 0, 0);
            unsigned p0 = h2bits(pk(fast_silu(acc[0])*Cc, fast_silu(acc[1])*Cc));
            unsigned p1 = h2bits(pk(fast_silu(acc[2])*Cc, fast_silu(acc[3])*Cc));
            if (ev) *reinterpret_cast<uint2*>(bufu + sb + 8*mt) = make_uint2(p0, p1);
        }
    }
}

// ---- node kernel v2: f16 dot2 comp_linear -----------------------------------
// sW uint4 layout [call][kp][u]: .x=w0 h2{k=2kp,2kp+1}, .y=w1, .z=w2, .w pad
// cb f16 layout per group: u32 word (kp*10 + c) = h2{cb[c][2kp], cb[c][2kp+1]}
//   c: 0=I, 1..3=A, 4..9=S. 160 u32 (640B) per group, 16B-aligned.
__device__ __forceinline__ void comp_linear2(
    const unsigned* __restrict__ sW, const unsigned* __restrict__ cbu,
    int u, int call, float& Il, float* a, float* s)
{
    const uint4* w4 = reinterpret_cast<const uint4*>(sW) + call*512 + u;
    const uint4* c4 = reinterpret_cast<const uint4*>(cbu);
    Il = 0.f; a[0]=a[1]=a[2]=0.f;
    s[0]=s[1]=s[2]=s[3]=s[4]=s[5]=0.f;
    #pragma unroll
    for (int kp2 = 0; kp2 < 8; ++kp2) {
        uint4 r0 = c4[kp2*5+0], r1 = c4[kp2*5+1], r2 = c4[kp2*5+2],
              r3 = c4[kp2*5+3], r4 = c4[kp2*5+4];
        uint4 w0 = w4[(2*kp2)*32], w1 = w4[(2*kp2+1)*32];
        // kp = 2*kp2
        Il   = dot2(as_h2(r0.x), as_h2(w0.x), Il);
        a[0] = dot2(as_h2(r0.y), as_h2(w0.y), a[0]);
        a[1] = dot2(as_h2(r0.z), as_h2(w0.y), a[1]);
        a[2] = dot2(as_h2(r0.w), as_h2(w0.y), a[2]);
        s[0] = dot2(as_h2(r1.x), as_h2(w0.z), s[0]);
        s[1] = dot2(as_h2(r1.y), as_h2(w0.z), s[1]);
        s[2] = dot2(as_h2(r1.z), as_h2(w0.z), s[2]);
        s[3] = dot2(as_h2(r1.w), as_h2(w0.z), s[3]);
        s[4] = dot2(as_h2(r2.x), as_h2(w0.z), s[4]);
        s[5] = dot2(as_h2(r2.y), as_h2(w0.z), s[5]);
        // kp = 2*kp2+1
        Il   = dot2(as_h2(r2.z), as_h2(w1.x), Il);
        a[0] = dot2(as_h2(r2.w), as_h2(w1.y), a[0]);
        a[1] = dot2(as_h2(r3.x), as_h2(w1.y), a[1]);
        a[2] = dot2(as_h2(r3.y), as_h2(w1.y), a[2]);
        s[0] = dot2(as_h2(r3.z), as_h2(w1.z), s[0]);
        s[1] = dot2(as_h2(r3.w), as_h2(w1.z), s[1]);
        s[2] = dot2(as_h2(r4.x), as_h2(w1.z), s[2]);
        s[3] = dot2(as_h2(r4.y), as_h2(w1.z), s[3]);
        s[4] = dot2(as_h2(r4.z), as_h2(w1.z), s[4]);
        s[5] = dot2(as_h2(r4.w), as_h2(w1.z), s[5]);
    }
}

__device__ __forceinline__ void compose(float Il, const float* a, const float* s, float (&T)[3][3])
{
    T[0][0] =  Il  + s[0]; T[0][1] =  a[0] + s[1]; T[0][2] =  a[1] + s[2];
    T[1][0] = -a[0] + s[1]; T[1][1] =  Il  + s[3]; T[1][2] =  a[2] + s[4];
    T[2][0] = -a[1] + s[2]; T[2][1] = -a[2] + s[4]; T[2][2] =  Il  + s[5];
}

__global__ __launch_bounds__(256) void node_kernel(
    const float* __restrict__ X,
    const unsigned* __restrict__ whn,
    const int* __restrict__ rowptr,
    const float* __restrict__ buf,
    float* __restrict__ out, int nN)
{
    __shared__ __align__(16) unsigned sW[4096];     // 16KB f16 weights
    __shared__ __align__(16) _Float16 sC[8][320];   // 5KB cb (f16)

    int tid = threadIdx.x;
    {
        const uint4* g4 = reinterpret_cast<const uint4*>(whn);
        uint4* s4 = reinterpret_cast<uint4*>(sW);
        #pragma unroll
        for (int i = 0; i < 4; ++i) s4[tid + 256*i] = g4[tid + 256*i];
    }

    int ln = tid >> 5, u = tid & 31;
    int n  = blockIdx.x * 8 + ln;
    if (n >= nN) n = nN - 1;
    const unsigned* cbu = reinterpret_cast<const unsigned*>(&sC[ln][0]);
    _Float16* cw = &sC[ln][(u >> 1)*20 + (u & 1)];

    int r0 = rowptr[n], r1 = rowptr[n + 1];
    float sIv = 0.f, sAv = 0.f, sSv = 0.f;
    const _Float16* bp = reinterpret_cast<const _Float16*>(buf) + (size_t)r0 * 96 + u;
    for (int i = r0; i < r1; ++i, bp += 96) {
        sIv += (float)bp[0];    // I plane
        sAv += (float)bp[32];   // A plane
        sSv += (float)bp[64];   // S plane
    }

    const float* xp = X + (size_t)n * 288 + u;
    float x[3][3];
    float nrm = 1.0f;
    #pragma unroll
    for (int i = 0; i < 3; ++i)
        #pragma unroll
        for (int j = 0; j < 3; ++j) {
            float v = xp[(i*3 + j) * 32];
            x[i][j] = v; nrm += v * v;
        }
    float inv = 1.0f / nrm;
    #pragma unroll
    for (int i = 0; i < 3; ++i)
        #pragma unroll
        for (int j = 0; j < 3; ++j) x[i][j] *= inv;

    float tI = (x[0][0] + x[1][1] + x[2][2]) * (1.0f/3.0f);
    cw[0]  = (_Float16)tI;
    cw[2]  = (_Float16)(0.5f * (x[0][1] - x[1][0]));
    cw[4]  = (_Float16)(0.5f * (x[0][2] - x[2][0]));
    cw[6]  = (_Float16)(0.5f * (x[1][2] - x[2][1]));
    cw[8]  = (_Float16)(x[0][0] - tI);
    cw[10] = (_Float16)(0.5f * (x[0][1] + x[1][0]));
    cw[12] = (_Float16)(0.5f * (x[0][2] + x[2][0]));
    cw[14] = (_Float16)(x[1][1] - tI);
    cw[16] = (_Float16)(0.5f * (x[1][2] + x[2][1]));
    cw[18] = (_Float16)(x[2][2] - tI);
    __syncthreads();   // sW staging + cb publish

    float Il, a[3], s[6];
    comp_linear2(sW, cbu, u, 0, Il, a, s);

    float Ym[3][3], Gm[3][3];
    compose(Il, a, s, Ym);
    float am[3] = {a[0]*sAv, a[1]*sAv, a[2]*sAv};
    float sm[6] = {s[0]*sSv, s[1]*sSv, s[2]*sSv, s[3]*sSv, s[4]*sSv, s[5]*sSv};
    compose(Il * sIv, am, sm, Gm);

    float M[3][3]; float np1 = 1.0f;
    #pragma unroll
    for (int i = 0; i < 3; ++i)
        #pragma unroll
        for (int l = 0; l < 3; ++l) {
            float v = 0.f;
            #pragma unroll
            for (int j = 0; j < 3; ++j) v += Ym[i][j]*Gm[j][l] + Gm[i][j]*Ym[j][l];
            M[i][l] = v; np1 += v * v;
        }
    float rinv = 1.0f / np1;
    float tI2 = (M[0][0] + M[1][1] + M[2][2]) * (1.0f/3.0f);

    // cb region is private to this 32-lane group (subset of the wave); DS ops
    // are wave-ordered -> wave_barrier only (no block barrier), as in R9.
    __builtin_amdgcn_wave_barrier();
    cw[0]  = (_Float16)(tI2 * rinv);
    cw[2]  = (_Float16)(0.5f * (M[0][1] - M[1][0]) * rinv);
    cw[4]  = (_Float16)(0.5f * (M[0][2] - M[2][0]) * rinv);
    cw[6]  = (_Float16)(0.5f * (M[1][2] - M[2][1]) * rinv);
    cw[8]  = (_Float16)((M[0][0] - tI2) * rinv);
    cw[10] = (_Float16)(0.5f * (M[0][1] + M[1][0]) * rinv);
    cw[12] = (_Float16)(0.5f * (M[0][2] + M[2][0]) * rinv);
    cw[14] = (_Float16)((M[1][1] - tI2) * rinv);
    cw[16] = (_Float16)(0.5f * (M[1][2] + M[2][1]) * rinv);
    cw[18] = (_Float16)((M[2][2] - tI2) * rinv);
    __builtin_amdgcn_wave_barrier();

    comp_linear2(sW, cbu, u, 1, Il, a, s);
    float D[3][3];
    compose(Il, a, s, D);

    float* op = out + (size_t)n * 288 + u;
    #pragma unroll
    for (int i = 0; i < 3; ++i)
        #pragma unroll
        for (int l = 0; l < 3; ++l) {
            float v = x[i][l] + D[i][l];
            #pragma unroll
            for (int j = 0; j < 3; ++j) v += D[i][j] * D[j][l];
            op[(i*3 + l) * 32] = v;
        }
}

extern "C" void kernel_launch(void* const* d_in, const int* in_sizes, int n_in,
                              void* d_out, int out_size, void* d_ws, size_t ws_size,
                              hipStream_t stream) {
    const float* X   = (const float*)d_in[0];
    const int*   ei  = (const int*)d_in[1];
    const float* ew  = (const float*)d_in[2];
    const float* ea  = (const float*)d_in[3];
    const float* W1  = (const float*)d_in[4];
    const float* b1  = (const float*)d_in[5];
    const float* W2  = (const float*)d_in[6];
    const float* b2  = (const float*)d_in[7];
    const float* W3  = (const float*)d_in[8];
    const float* b3  = (const float*)d_in[9];
    const float* Wt  = (const float*)d_in[10];

    int nE = in_sizes[2];          // 400000
    int nN = in_sizes[0] / 288;    // 50000
    int nChunks = (nN + 1023) / 1024;

    float* ws       = (float*)d_ws;
    unsigned* whn   = (unsigned*)ws;             // 4096 u32 (16KB), region padded to 8192 f
    float* ball     = ws + 8192;                 // 192 floats (pad to 256)
    unsigned* wfrag = (unsigned*)(ws + 8448);    // 4608 u32 MFMA weight frags
    float* buf      = ws + 8448 + 4608;          // nE*48 floats (= nE*96 halves)
    size_t buf_f    = (size_t)nE * 48;
    int* ib     = (int*)(buf + buf_f);
    int* cntA   = ib;                 // nN
    int* cursor = ib + nN;            // nN
    int* rowptr = ib + 2 * nN;        // nN+1
    int* csum   = ib + 3 * nN + 1;    // nChunks (<=64)

    prep_kernel<<<36, 256, 0, stream>>>(Wt, W1, b1, W2, b2, W3, b3, whn, ball, wfrag);
    (void)hipMemsetAsync(cntA, 0, (size_t)2 * nN * sizeof(int), stream);
    hist_kernel<<<(nE + 255) / 256, 256, 0, stream>>>(ei, cntA, nE);
    scanA_kernel<<<nChunks, 1024, 0, stream>>>(cntA, rowptr, csum, nN);
    scanB_kernel<<<1, 64, 0, stream>>>(csum, rowptr, nChunks, nN);
    scanC_kernel<<<nChunks, 1024, 0, stream>>>(csum, rowptr, nN);
    edge_mfma_kernel<<<768, 256, 0, stream>>>(
        ea, ew, ei, rowptr, cursor, wfrag, ball, buf, nE);
    node_kernel<<<(nN + 7) / 8, 256, 0, stream>>>(
        X, whn, rowptr, buf, (float*)d_out, nN);
}

// Round 5
// 270.699 us; speedup vs baseline: 1.3628x; 1.0012x over previous
//
#include <hip/hip_runtime.h>
#include <math.h>

// N=50000, E=400000, U=32, R=32. All fp32 inputs; edge_index int32.
//
// R10 (271.0 us): node f16-dot2 comp_linear -> node below top-5 (<65us).
//   Edge_mfma now #1: 65.6us, occ 25%, VALU 29%, Mfma 4%, HBM 23%,
//   no pipe saturated -> latency-bound at 768 blocks (3 blk/CU = 37.5% cap;
//   VGPR 84 + 1KB LDS would allow 6 blk/CU = 75%).
// R11 (this round), one lever + two enablers, edge kernel only:
//   (1) grid 768 -> 1536 blocks (max resident; occupancy cap 37.5 -> 75%),
//   (2) rowptr[dst] prefetched one tile ahead (was a dependent L2 load at
//       iteration start),
//   (3) cursor atomicAdd + slot shfl hoisted to top of loop body: ~300cy
//       atomic latency now overlaps all 3 MFMA layers (slot order within a
//       node's CSR range is arbitrary -> semantics unchanged).
//   Node/CSR/prep kernels untouched.

typedef _Float16 h2    __attribute__((ext_vector_type(2)));
typedef __fp16   p2    __attribute__((ext_vector_type(2)));
typedef _Float16 f16x8 __attribute__((ext_vector_type(8)));
typedef float    f32x4 __attribute__((ext_vector_type(4)));

union U8 { unsigned u[4]; uint4 q; f16x8 v; };
union C4 { float4 f; f32x4 v; };

__device__ __forceinline__ h2 as_h2(unsigned u){ union{unsigned x; h2 h;} c; c.x=u; return c.h; }
__device__ __forceinline__ unsigned h2bits(h2 h){ union{h2 h; unsigned x;} c; c.h=h; return c.x; }

__device__ __forceinline__ float dot2(h2 a, h2 b, float c){
#if __has_builtin(__builtin_amdgcn_fdot2)
    return __builtin_amdgcn_fdot2(a, b, c, false);
#else
    return c + (float)a.x*(float)b.x + (float)a.y*(float)b.y;
#endif
}

__device__ __forceinline__ h2 pk(float a, float b){
#if __has_builtin(__builtin_amdgcn_cvt_pkrtz)
    union { p2 p; h2 h; } c;
    c.p = __builtin_amdgcn_cvt_pkrtz(a, b);
    return c.h;
#else
    h2 r; r.x=(_Float16)a; r.y=(_Float16)b; return r;
#endif
}

// round-to-nearest f16 pack (for node path precision)
__device__ __forceinline__ unsigned pk_rtn(float a, float b){
    union { h2 h; unsigned x; } c;
    c.h.x = (_Float16)a; c.h.y = (_Float16)b;
    return c.x;
}

__device__ __forceinline__ float fast_silu(float x){
    return x * __builtin_amdgcn_rcpf(1.0f + __expf(-x));
}

// ---- prep ------------------------------------------------------------------
// whn  : node tensor weights f16: uint4[2 call][16 kp][32 u], word c<3 =
//        h2{Wt[3*call+c][u][2kp], Wt[3*call+c][u][2kp+1]}, word3 = 0
// ball : [b1(32) | b2(64) | b3 permuted to o=c*32+u order (96)]  f32
// wfrag: 18 MFMA A-fragments x 64 lanes x 4 u32 (packed f16 pairs)
__global__ __launch_bounds__(256) void prep_kernel(
    const float* __restrict__ Wt,
    const float* __restrict__ W1, const float* __restrict__ b1,
    const float* __restrict__ W2, const float* __restrict__ b2,
    const float* __restrict__ W3, const float* __restrict__ b3,
    unsigned* __restrict__ whn, float* __restrict__ ball, unsigned* __restrict__ wfrag)
{
    int i = blockIdx.x * 256 + threadIdx.x;
    if (i < 4096) {
        int call = i >> 11, r = i & 2047, kp = r >> 7, rem = r & 127;
        int u = rem >> 2, c = rem & 3;
        unsigned val = 0;
        if (c < 3) {
            const float* W = Wt + (size_t)(3*call + c)*1024 + u*32 + 2*kp;
            val = pk_rtn(W[0], W[1]);
        }
        whn[i] = val;
    }
    if (i < 192) {
        float v;
        if (i < 32)      v = b1[i];
        else if (i < 96) v = b2[i-32];
        else {
            int o = i - 96;                       // output slot o = c*32+u
            v = b3[(o & 31)*3 + (o >> 5)];        // original row m = u*3+c
        }
        ball[i] = v;
    }
    if (i < 4608) {
        int f = i >> 8, l = (i >> 2) & 63, wi = i & 3;
        int row = l & 15, qq = l >> 4;
        int kb = 8*qq + 2*wi;
        float v0, v1;
        if (f < 2) {
            int m = 16*f + row;
            v0 = W1[m*32 + kb]; v1 = W1[m*32 + kb + 1];
        } else if (f < 6) {
            int m = 16*(f-2) + row;
            v0 = W2[m*32 + kb]; v1 = W2[m*32 + kb + 1];
        } else {
            int idx = f - 6, mt = idx >> 1, kh = idx & 1;
            int mp = 16*mt + row;
            int om = (mp & 31)*3 + (mp >> 5);
            int k  = 32*kh + kb;
            v0 = W3[om*64 + k]; v1 = W3[om*64 + k + 1];
        }
        wfrag[i] = pk_rtn(v0, v1);
    }
}

// ---- CSR build ---------------------------------------------------------------
__global__ __launch_bounds__(256) void hist_kernel(
    const int* __restrict__ edge_index, int* __restrict__ cnt, int nE)
{
    int e = blockIdx.x * 256 + threadIdx.x;
    if (e < nE) atomicAdd(&cnt[edge_index[nE + e]], 1);
}

__global__ __launch_bounds__(1024) void scanA_kernel(
    const int* __restrict__ cnt, int* __restrict__ rowptr,
    int* __restrict__ csum, int nN)
{
    __shared__ int wsum[16];
    __shared__ int wpre[16];
    int tid = threadIdx.x, lane = tid & 63, wid = tid >> 6;
    int i = blockIdx.x * 1024 + tid;
    int orig = (i < nN) ? cnt[i] : 0;
    int v = orig;
    #pragma unroll
    for (int d = 1; d < 64; d <<= 1) { int o = __shfl_up(v, d); if (lane >= d) v += o; }
    if (lane == 63) wsum[wid] = v;
    __syncthreads();
    if (wid == 0) {
        int s = (lane < 16) ? wsum[lane] : 0;
        #pragma unroll
        for (int d = 1; d < 16; d <<= 1) { int o = __shfl_up(s, d); if (lane >= d) s += o; }
        if (lane < 16) wpre[lane] = s;
    }
    __syncthreads();
    int badd = wid ? wpre[wid - 1] : 0;
    if (i < nN) rowptr[i] = badd + v - orig;
    if (tid == 1023) csum[blockIdx.x] = badd + v;
}

__global__ __launch_bounds__(64) void scanB_kernel(
    int* __restrict__ csum, int* __restrict__ rowptr, int nChunks, int nN)
{
    int lane = threadIdx.x;
    int orig = (lane < nChunks) ? csum[lane] : 0;
    int s = orig;
    #pragma unroll
    for (int d = 1; d < 64; d <<= 1) { int o = __shfl_up(s, d); if (lane >= d) s += o; }
    if (lane < nChunks) csum[lane] = s - orig;
    if (lane == 63) rowptr[nN] = s;
}

__global__ __launch_bounds__(1024) void scanC_kernel(
    const int* __restrict__ csum, int* __restrict__ rowptr, int nN)
{
    int i = blockIdx.x * 1024 + threadIdx.x;
    if (i < nN) rowptr[i] += csum[i >> 10];
}

// ---- edge: MFMA MLP ---------------------------------------------------------
// One wave = 16 edges. Transposed: D[m][e] = sum_k W[m][k] act[e][k] + b[m].
// D layout (m89-verified): col(e)=lane&15, row(m)=(lane>>4)*4+r.
// A/B layout: row/col = lane&15, k = 8*(lane>>4)+j (contiguous k, b128-style).
__global__ __launch_bounds__(256) void edge_mfma_kernel(
    const float* __restrict__ edge_attr,
    const float* __restrict__ edge_weight,
    const int* __restrict__ edge_index,
    const int* __restrict__ rowptr,
    int* __restrict__ cursor,
    const unsigned* __restrict__ wfrag,
    const float* __restrict__ ball,
    float* __restrict__ buf, int nE)
{
    __shared__ __align__(16) float sball[192];
    int tid = threadIdx.x;
    if (tid < 192) sball[tid] = ball[tid];
    __syncthreads();

    int lane = tid & 63;
    int wid  = (blockIdx.x << 2) + (tid >> 6);
    int nW   = gridDim.x << 2;
    int T    = (nE + 15) >> 4;

    U8 aw[18];
    #pragma unroll
    for (int f = 0; f < 18; ++f)
        aw[f].q = reinterpret_cast<const uint4*>(wfrag)[f*64 + lane];

    int q = lane >> 4, ecol = lane & 15;
    bool hiq = lane >= 32;
    int sl = ecol + ((lane & 16) << 1);
    int sh = sl + 16;

    unsigned* bufu = reinterpret_cast<unsigned*>(buf);

    // prefetch first tile (incl. dst node and its rowptr)
    int tile = wid;
    float4 pA = make_float4(0,0,0,0), pB = pA; float pew = 0.f;
    int pd = 0, prp = 0;
    if (tile < T) {
        int e = tile*16 + ecol; if (e >= nE) e = nE - 1;
        const float* eap = edge_attr + (size_t)e*32 + q*8;
        pA = *reinterpret_cast<const float4*>(eap);
        pB = *reinterpret_cast<const float4*>(eap + 4);
        pew = edge_weight[e];
        if (lane < 16) { pd = edge_index[nE + e]; prp = rowptr[pd]; }
    }

    for (; tile < T; tile += nW) {
        float4 cA = pA, cB = pB; float ew = pew; int d = pd, rp = prp;
        bool ev = (tile*16 + ecol) < nE;

        // slot atomic first: ~300cy L2 latency overlaps all 3 MFMA layers.
        int slot = 0;
        if (lane < 16 && ev) slot = rp + atomicAdd(&cursor[d], 1);
        int slotAll = __shfl(slot, ecol);

        // prefetch next tile
        int nt = tile + nW;
        if (nt < T) {
            int e = nt*16 + ecol; if (e >= nE) e = nE - 1;
            const float* eap = edge_attr + (size_t)e*32 + q*8;
            pA = *reinterpret_cast<const float4*>(eap);
            pB = *reinterpret_cast<const float4*>(eap + 4);
            pew = edge_weight[e];
            if (lane < 16) { pd = edge_index[nE + e]; prp = rowptr[pd]; }
        }

        // B_ea: col=edge, k=8q+j
        U8 bea;
        bea.u[0] = h2bits(pk(cA.x, cA.y));
        bea.u[1] = h2bits(pk(cA.z, cA.w));
        bea.u[2] = h2bits(pk(cB.x, cB.y));
        bea.u[3] = h2bits(pk(cB.z, cB.w));

        // ---- layer 1: h1T(32xE) = silu(W1 @ eaT + b1) ----
        unsigned w1w[4];
        #pragma unroll
        for (int t = 0; t < 2; ++t) {
            C4 c; c.f = *reinterpret_cast<const float4*>(&sball[16*t + 4*q]);
            f32x4 acc = c.v;
            acc = __builtin_amdgcn_mfma_f32_16x16x32_f16(aw[t].v, bea.v, acc, 0, 0, 0);
            w1w[2*t]   = h2bits(pk(fast_silu(acc[0]), fast_silu(acc[1])));
            w1w[2*t+1] = h2bits(pk(fast_silu(acc[2]), fast_silu(acc[3])));
        }

        // transpose D->B
        U8 bh1;
        {
            unsigned t0 = (unsigned)__shfl((int)w1w[0], sl), t2 = (unsigned)__shfl((int)w1w[2], sl);
            bh1.u[0] = hiq ? t2 : t0;
            unsigned t1 = (unsigned)__shfl((int)w1w[1], sl), t3 = (unsigned)__shfl((int)w1w[3], sl);
            bh1.u[1] = hiq ? t3 : t1;
            t0 = (unsigned)__shfl((int)w1w[0], sh); t2 = (unsigned)__shfl((int)w1w[2], sh);
            bh1.u[2] = hiq ? t2 : t0;
            t1 = (unsigned)__shfl((int)w1w[1], sh); t3 = (unsigned)__shfl((int)w1w[3], sh);
            bh1.u[3] = hiq ? t3 : t1;
        }

        // ---- layer 2: h2T(64xE) = silu(W2 @ h1T + b2) ----
        unsigned w2w[8];
        #pragma unroll
        for (int t = 0; t < 4; ++t) {
            C4 c; c.f = *reinterpret_cast<const float4*>(&sball[32 + 16*t + 4*q]);
            f32x4 acc = c.v;
            acc = __builtin_amdgcn_mfma_f32_16x16x32_f16(aw[2+t].v, bh1.v, acc, 0, 0, 0);
            w2w[2*t]   = h2bits(pk(fast_silu(acc[0]), fast_silu(acc[1])));
            w2w[2*t+1] = h2bits(pk(fast_silu(acc[2]), fast_silu(acc[3])));
        }

        // transpose -> two B-frags (k-halves of 64)
        U8 b3f[2];
        #pragma unroll
        for (int h = 0; h < 2; ++h) {
            unsigned ta = (unsigned)__shfl((int)w2w[4*h],   sl), tb = (unsigned)__shfl((int)w2w[4*h+2], sl);
            b3f[h].u[0] = hiq ? tb : ta;
            unsigned tc = (unsigned)__shfl((int)w2w[4*h+1], sl), td = (unsigned)__shfl((int)w2w[4*h+3], sl);
            b3f[h].u[1] = hiq ? td : tc;
            ta = (unsigned)__shfl((int)w2w[4*h],   sh); tb = (unsigned)__shfl((int)w2w[4*h+2], sh);
            b3f[h].u[2] = hiq ? tb : ta;
            tc = (unsigned)__shfl((int)w2w[4*h+1], sh); td = (unsigned)__shfl((int)w2w[4*h+3], sh);
            b3f[h].u[3] = hiq ? td : tc;
        }

        float Cc = (ew < 5.0f) ? 0.5f * (__cosf(ew * 0.6283185307179586f) + 1.0f) : 0.0f;

        // ---- layer 3: out(96xE) = silu(W3p @ h2T + b3p) * Cc ----
        size_t sb = (size_t)slotAll * 48 + 2*q;
        #pragma unroll
        for (int mt = 0; mt < 6; ++mt) {
            C4 c; c.f = *reinterpret_cast<const float4*>(&sball[96 + 16*mt + 4*q]);
            f32x4 acc = c.v;
            acc = __builtin_amdgcn_mfma_f32_16x16x32_f16(aw[6+2*mt].v, b3f[0].v, acc, 0, 0, 0);
            acc = __builtin_amdgcn_mfma_f32_16x16x32_f16(aw[7+2*mt].v, b3f[1].v, acc, 0, 0, 0);
            unsigned p0 = h2bits(pk(fast_silu(acc[0])*Cc, fast_silu(acc[1])*Cc));
            unsigned p1 = h2bits(pk(fast_silu(acc[2])*Cc, fast_silu(acc[3])*Cc));
            if (ev) *reinterpret_cast<uint2*>(bufu + sb + 8*mt) = make_uint2(p0, p1);
        }
    }
}

// ---- node kernel v2: f16 dot2 comp_linear (unchanged from R10) --------------
__device__ __forceinline__ void comp_linear2(
    const unsigned* __restrict__ sW, const unsigned* __restrict__ cbu,
    int u, int call, float& Il, float* a, float* s)
{
    const uint4* w4 = reinterpret_cast<const uint4*>(sW) + call*512 + u;
    const uint4* c4 = reinterpret_cast<const uint4*>(cbu);
    Il = 0.f; a[0]=a[1]=a[2]=0.f;
    s[0]=s[1]=s[2]=s[3]=s[4]=s[5]=0.f;
    #pragma unroll
    for (int kp2 = 0; kp2 < 8; ++kp2) {
        uint4 r0 = c4[kp2*5+0], r1 = c4[kp2*5+1], r2 = c4[kp2*5+2],
              r3 = c4[kp2*5+3], r4 = c4[kp2*5+4];
        uint4 w0 = w4[(2*kp2)*32], w1 = w4[(2*kp2+1)*32];
        Il   = dot2(as_h2(r0.x), as_h2(w0.x), Il);
        a[0] = dot2(as_h2(r0.y), as_h2(w0.y), a[0]);
        a[1] = dot2(as_h2(r0.z), as_h2(w0.y), a[1]);
        a[2] = dot2(as_h2(r0.w), as_h2(w0.y), a[2]);
        s[0] = dot2(as_h2(r1.x), as_h2(w0.z), s[0]);
        s[1] = dot2(as_h2(r1.y), as_h2(w0.z), s[1]);
        s[2] = dot2(as_h2(r1.z), as_h2(w0.z), s[2]);
        s[3] = dot2(as_h2(r1.w), as_h2(w0.z), s[3]);
        s[4] = dot2(as_h2(r2.x), as_h2(w0.z), s[4]);
        s[5] = dot2(as_h2(r2.y), as_h2(w0.z), s[5]);
        Il   = dot2(as_h2(r2.z), as_h2(w1.x), Il);
        a[0] = dot2(as_h2(r2.w), as_h2(w1.y), a[0]);
        a[1] = dot2(as_h2(r3.x), as_h2(w1.y), a[1]);
        a[2] = dot2(as_h2(r3.y), as_h2(w1.y), a[2]);
        s[0] = dot2(as_h2(r3.z), as_h2(w1.z), s[0]);
        s[1] = dot2(as_h2(r3.w), as_h2(w1.z), s[1]);
        s[2] = dot2(as_h2(r4.x), as_h2(w1.z), s[2]);
        s[3] = dot2(as_h2(r4.y), as_h2(w1.z), s[3]);
        s[4] = dot2(as_h2(r4.z), as_h2(w1.z), s[4]);
        s[5] = dot2(as_h2(r4.w), as_h2(w1.z), s[5]);
    }
}

__device__ __forceinline__ void compose(float Il, const float* a, const float* s, float (&T)[3][3])
{
    T[0][0] =  Il  + s[0]; T[0][1] =  a[0] + s[1]; T[0][2] =  a[1] + s[2];
    T[1][0] = -a[0] + s[1]; T[1][1] =  Il  + s[3]; T[1][2] =  a[2] + s[4];
    T[2][0] = -a[1] + s[2]; T[2][1] = -a[2] + s[4]; T[2][2] =  Il  + s[5];
}

__global__ __launch_bounds__(256) void node_kernel(
    const float* __restrict__ X,
    const unsigned* __restrict__ whn,
    const int* __restrict__ rowptr,
    const float* __restrict__ buf,
    float* __restrict__ out, int nN)
{
    __shared__ __align__(16) unsigned sW[4096];     // 16KB f16 weights
    __shared__ __align__(16) _Float16 sC[8][320];   // 5KB cb (f16)

    int tid = threadIdx.x;
    {
        const uint4* g4 = reinterpret_cast<const uint4*>(whn);
        uint4* s4 = reinterpret_cast<uint4*>(sW);
        #pragma unroll
        for (int i = 0; i < 4; ++i) s4[tid + 256*i] = g4[tid + 256*i];
    }

    int ln = tid >> 5, u = tid & 31;
    int n  = blockIdx.x * 8 + ln;
    if (n >= nN) n = nN - 1;
    const unsigned* cbu = reinterpret_cast<const unsigned*>(&sC[ln][0]);
    _Float16* cw = &sC[ln][(u >> 1)*20 + (u & 1)];

    int r0 = rowptr[n], r1 = rowptr[n + 1];
    float sIv = 0.f, sAv = 0.f, sSv = 0.f;
    const _Float16* bp = reinterpret_cast<const _Float16*>(buf) + (size_t)r0 * 96 + u;
    for (int i = r0; i < r1; ++i, bp += 96) {
        sIv += (float)bp[0];    // I plane
        sAv += (float)bp[32];   // A plane
        sSv += (float)bp[64];   // S plane
    }

    const float* xp = X + (size_t)n * 288 + u;
    float x[3][3];
    float nrm = 1.0f;
    #pragma unroll
    for (int i = 0; i < 3; ++i)
        #pragma unroll
        for (int j = 0; j < 3; ++j) {
            float v = xp[(i*3 + j) * 32];
            x[i][j] = v; nrm += v * v;
        }
    float inv = 1.0f / nrm;
    #pragma unroll
    for (int i = 0; i < 3; ++i)
        #pragma unroll
        for (int j = 0; j < 3; ++j) x[i][j] *= inv;

    float tI = (x[0][0] + x[1][1] + x[2][2]) * (1.0f/3.0f);
    cw[0]  = (_Float16)tI;
    cw[2]  = (_Float16)(0.5f * (x[0][1] - x[1][0]));
    cw[4]  = (_Float16)(0.5f * (x[0][2] - x[2][0]));
    cw[6]  = (_Float16)(0.5f * (x[1][2] - x[2][1]));
    cw[8]  = (_Float16)(x[0][0] - tI);
    cw[10] = (_Float16)(0.5f * (x[0][1] + x[1][0]));
    cw[12] = (_Float16)(0.5f * (x[0][2] + x[2][0]));
    cw[14] = (_Float16)(x[1][1] - tI);
    cw[16] = (_Float16)(0.5f * (x[1][2] + x[2][1]));
    cw[18] = (_Float16)(x[2][2] - tI);
    __syncthreads();   // sW staging + cb publish

    float Il, a[3], s[6];
    comp_linear2(sW, cbu, u, 0, Il, a, s);

    float Ym[3][3], Gm[3][3];
    compose(Il, a, s, Ym);
    float am[3] = {a[0]*sAv, a[1]*sAv, a[2]*sAv};
    float sm[6] = {s[0]*sSv, s[1]*sSv, s[2]*sSv, s[3]*sSv, s[4]*sSv, s[5]*sSv};
    compose(Il * sIv, am, sm, Gm);

    float M[3][3]; float np1 = 1.0f;
    #pragma unroll
    for (int i = 0; i < 3; ++i)
        #pragma unroll
        for (int l = 0; l < 3; ++l) {
            float v = 0.f;
            #pragma unroll
            for (int j = 0; j < 3; ++j) v += Ym[i][j]*Gm[j][l] + Gm[i][j]*Ym[j][l];
            M[i][l] = v; np1 += v * v;
        }
    float rinv = 1.0f / np1;
    float tI2 = (M[0][0] + M[1][1] + M[2][2]) * (1.0f/3.0f);

    __builtin_amdgcn_wave_barrier();
    cw[0]  = (_Float16)(tI2 * rinv);
    cw[2]  = (_Float16)(0.5f * (M[0][1] - M[1][0]) * rinv);
    cw[4]  = (_Float16)(0.5f * (M[0][2] - M[2][0]) * rinv);
    cw[6]  = (_Float16)(0.5f * (M[1][2] - M[2][1]) * rinv);
    cw[8]  = (_Float16)((M[0][0] - tI2) * rinv);
    cw[10] = (_Float16)(0.5f * (M[0][1] + M[1][0]) * rinv);
    cw[12] = (_Float16)(0.5f * (M[0][2] + M[2][0]) * rinv);
    cw[14] = (_Float16)((M[1][1] - tI2) * rinv);
    cw[16] = (_Float16)(0.5f * (M[1][2] + M[2][1]) * rinv);
    cw[18] = (_Float16)((M[2][2] - tI2) * rinv);
    __builtin_amdgcn_wave_barrier();

    comp_linear2(sW, cbu, u, 1, Il, a, s);
    float D[3][3];
    compose(Il, a, s, D);

    float* op = out + (size_t)n * 288 + u;
    #pragma unroll
    for (int i = 0; i < 3; ++i)
        #pragma unroll
        for (int l = 0; l < 3; ++l) {
            float v = x[i][l] + D[i][l];
            #pragma unroll
            for (int j = 0; j < 3; ++j) v += D[i][j] * D[j][l];
            op[(i*3 + l) * 32] = v;
        }
}

extern "C" void kernel_launch(void* const* d_in, const int* in_sizes, int n_in,
                              void* d_out, int out_size, void* d_ws, size_t ws_size,
                              hipStream_t stream) {
    const float* X   = (const float*)d_in[0];
    const int*   ei  = (const int*)d_in[1];
    const float* ew  = (const float*)d_in[2];
    const float* ea  = (const float*)d_in[3];
    const float* W1  = (const float*)d_in[4];
    const float* b1  = (const float*)d_in[5];
    const float* W2  = (const float*)d_in[6];
    const float* b2  = (const float*)d_in[7];
    const float* W3  = (const float*)d_in[8];
    const float* b3  = (const float*)d_in[9];
    const float* Wt  = (const float*)d_in[10];

    int nE = in_sizes[2];          // 400000
    int nN = in_sizes[0] / 288;    // 50000
    int nChunks = (nN + 1023) / 1024;

    float* ws       = (float*)d_ws;
    unsigned* whn   = (unsigned*)ws;             // 4096 u32 (16KB), region padded to 8192 f
    float* ball     = ws + 8192;                 // 192 floats (pad to 256)
    unsigned* wfrag = (unsigned*)(ws + 8448);    // 4608 u32 MFMA weight frags
    float* buf      = ws + 8448 + 4608;          // nE*48 floats (= nE*96 halves)
    size_t buf_f    = (size_t)nE * 48;
    int* ib     = (int*)(buf + buf_f);
    int* cntA   = ib;                 // nN
    int* cursor = ib + nN;            // nN
    int* rowptr = ib + 2 * nN;        // nN+1
    int* csum   = ib + 3 * nN + 1;    // nChunks (<=64)

    prep_kernel<<<36, 256, 0, stream>>>(Wt, W1, b1, W2, b2, W3, b3, whn, ball, wfrag);
    (void)hipMemsetAsync(cntA, 0, (size_t)2 * nN * sizeof(int), stream);
    hist_kernel<<<(nE + 255) / 256, 256, 0, stream>>>(ei, cntA, nE);
    scanA_kernel<<<nChunks, 1024, 0, stream>>>(cntA, rowptr, csum, nN);
    scanB_kernel<<<1, 64, 0, stream>>>(csum, rowptr, nChunks, nN);
    scanC_kernel<<<nChunks, 1024, 0, stream>>>(csum, rowptr, nN);
    edge_mfma_kernel<<<1536, 256, 0, stream>>>(
        ea, ew, ei, rowptr, cursor, wfrag, ball, buf, nE);
    node_kernel<<<(nN + 7) / 8, 256, 0, stream>>>(
        X, whn, rowptr, buf, (float*)d_out, nN);
}